// Round 2
// baseline (142.431 us; speedup 1.0000x reference)
//
#include <hip/hip_runtime.h>
#include <math.h>

// AutoAttention_Layer: B=1024, MAXLEN=200, F=64, D=64, fp32.
// Algebra: v unused; qk = Wk @ (Wq^T applied...) collapsed to three per-batch
// 64-GEMVs; single-pass softmax (unmasked logits in (0,0.125) -> no max-shift;
// masked exp underflows to exactly 0; len==0 -> uniform weights).
// Structure: whole k (51.2 KB) async-prefetched to LDS at kernel entry via
// global_load_lds width=16; prologue GEMVs hide the HBM latency; score dot
// uses a per-lane rotation swizzle so unpadded LDS stays <=2-way (free).

namespace {
constexpr int MAXLEN = 200;
constexpr int DD     = 64;

__device__ __forceinline__ void load_lds16(const float* g, float* l) {
    __builtin_amdgcn_global_load_lds(
        (const __attribute__((address_space(1))) void*)g,
        (__attribute__((address_space(3))) void*)l,
        16, 0, 0);
}

__global__ __launch_bounds__(256, 4)   // 128 VGPRs max: no spills; LDS caps us at 3 blocks/CU anyway
void auto_attn_kernel(const float* __restrict__ q,
                      const float* __restrict__ k,
                      const int*   __restrict__ kes_length,
                      const float* __restrict__ fs,
                      const float* __restrict__ bias,
                      const float* __restrict__ Wq,
                      const float* __restrict__ Wk,
                      const float* __restrict__ Wv,
                      float*       __restrict__ out)
{
    __shared__ float kt[MAXLEN * DD];   // 51200 B, unpadded (global_load_lds layout)
    __shared__ float red[256];
    __shared__ float vec[DD];           // qbar -> qw -> kbar (reused; barriers separate uses)
    __shared__ float qks[DD];
    __shared__ float sw[MAXLEN];
    __shared__ float sS[4];

    const int tid  = threadIdx.x;
    const int b    = blockIdx.x;
    const int lane = tid & 63;
    const int wave = tid >> 6;

    const float* kb = k + (size_t)b * (MAXLEN * DD);
    const float* qb = q + (size_t)b * (DD * DD);   // F == D == 64

    // ---- async prefetch: all of k -> LDS, 50 chunks of 1 KB (64 lanes x 16 B)
    // lds dest is wave-uniform base + lane*16; gptr matches -> contiguous copy.
    for (int j = wave; j < 50; j += 4)
        load_lds16(kb + j * 256 + lane * 4, &kt[j * 256]);

    const int len = kes_length[b];

    // ---- qbar[d] = sum_f fs[f] * q[b,f,d]   (coalesced over lanes = d)
    float acc = 0.f;
    #pragma unroll
    for (int i = 0; i < 16; ++i) {
        const int f = wave * 16 + i;
        acc += fs[f] * qb[f * 64 + lane];
    }
    red[tid] = acc;
    __syncthreads();                    // (also drains the k prefetch once)
    if (tid < 64) vec[tid] = red[tid] + red[tid + 64] + red[tid + 128] + red[tid + 192];
    __syncthreads();

    // ---- qw[e] = sum_d qbar[d] * Wq[d,e]   (Wq L2-hot across all blocks)
    acc = 0.f;
    #pragma unroll
    for (int i = 0; i < 16; ++i) {
        const int dd = wave * 16 + i;
        acc += vec[dd] * Wq[dd * 64 + lane];
    }
    red[tid] = acc;
    __syncthreads();
    if (tid < 64) vec[tid] = red[tid] + red[tid + 64] + red[tid + 128] + red[tid + 192];
    __syncthreads();

    // ---- qk[d] = sum_e Wk[d,e] * qw[e]     (row-gather of Wk; 16 KB, L1/L2-hot)
    acc = 0.f;
    #pragma unroll
    for (int i = 0; i < 16; ++i) {
        const int e = wave * 16 + i;
        acc += Wk[lane * 64 + e] * vec[e];
    }
    red[tid] = acc;
    __syncthreads();
    if (tid < 64) qks[tid] = red[tid] + red[tid + 64] + red[tid + 128] + red[tid + 192];
    __syncthreads();

    // ---- scores + weights: one thread per token, rotated dot (<=2-way banks)
    const float bscale = bias[0] * 64.0f;
    const int t = tid;
    if (t < MAXLEN) {
        float s = 0.f;
        #pragma unroll
        for (int i = 0; i < 64; ++i) {
            const int idx = (i + lane) & 63;
            s += kt[t * 64 + idx] * qks[idx];
        }
        s += bscale;
        float w;
        if (len == 0)      w = 1.0f;                            // uniform softmax
        else if (t < len) { const float sig = 1.0f / (1.0f + __expf(-s));
                            w = __expf(sig * 0.125f); }         // no max-shift needed
        else               w = 0.0f;                            // masked -> exactly 0
        sw[t] = w;
    }
    __syncthreads();

    // ---- kacc[d] = sum_t w[t]*k[t,d]; S = sum_t w[t]   (wave w: tokens [50w,50w+50))
    float kacc = 0.f, Sr = 0.f;
    #pragma unroll 10
    for (int i = 0; i < 50; ++i) {
        const int t2 = wave * 50 + i;
        const float w = sw[t2];          // broadcast
        kacc += w * kt[t2 * 64 + lane];  // 2-way banks, free
        Sr   += w;
    }
    red[tid] = kacc;
    if (lane == 0) sS[wave] = Sr;
    __syncthreads();
    if (tid < 64) {
        const float S = sS[0] + sS[1] + sS[2] + sS[3];   // >= 1 always
        vec[tid] = (red[tid] + red[tid + 64] + red[tid + 128] + red[tid + 192]) / S;
    }
    __syncthreads();

    // ---- out[b] = kbar @ Wv
    acc = 0.f;
    #pragma unroll
    for (int i = 0; i < 16; ++i) {
        const int dd = wave * 16 + i;
        acc += vec[dd] * Wv[dd * 64 + lane];
    }
    red[tid] = acc;
    __syncthreads();
    if (tid < 64)
        out[(size_t)b * 64 + tid] = red[tid] + red[tid + 64] + red[tid + 128] + red[tid + 192];
}
} // namespace

extern "C" void kernel_launch(void* const* d_in, const int* in_sizes, int n_in,
                              void* d_out, int out_size, void* d_ws, size_t ws_size,
                              hipStream_t stream) {
    const float* q    = (const float*)d_in[0];
    const float* k    = (const float*)d_in[1];
    // d_in[2] = v : unused by the reference (vp is computed from k)
    const int*   kes  = (const int*)  d_in[3];
    const float* fs   = (const float*)d_in[4];
    const float* bias = (const float*)d_in[5];
    const float* Wq   = (const float*)d_in[6];
    const float* Wk   = (const float*)d_in[7];
    const float* Wv   = (const float*)d_in[8];
    float* out = (float*)d_out;

    auto_attn_kernel<<<dim3(1024), dim3(256), 0, stream>>>(q, k, kes, fs, bias, Wq, Wk, Wv, out);
}

// Round 3
// 140.272 us; speedup vs baseline: 1.0154x; 1.0154x over previous
//
#include <hip/hip_runtime.h>
#include <math.h>

// AutoAttention_Layer: B=1024, MAXLEN=200, F=64, D=64, fp32.
// Algebra: v unused; the three DxD projections collapse to per-batch 64-GEMVs
// (qbar = sum_f fs[f] q[b,f,:]; qw = qbar@Wq; qk = Wk@qw; out = kbar@Wv);
// single-pass softmax: unmasked logits = sigmoid(.)/8 in (0,0.125) -> exp needs
// no max-shift; masked exp underflows to exactly 0; len==0 -> uniform weights.
// Structure: k never touches LDS. 4 threads per token hold 16-float k slices in
// registers; score completed via 2x shfl_xor; w computed redundantly per slice;
// weighted k accumulated in 16 VGPRs; one small LDS transpose at the end.
// LDS ~18 KB -> all 1024 blocks resident in a single dispatch wave (4/CU).

namespace {
constexpr int MAXLEN = 200;

__global__ __launch_bounds__(256, 4)   // 4 waves/EU -> 4 blocks/CU; VGPR cap 128
void auto_attn_kernel(const float* __restrict__ q,
                      const float* __restrict__ k,
                      const int*   __restrict__ kes_length,
                      const float* __restrict__ fs,
                      const float* __restrict__ bias,
                      const float* __restrict__ Wq,
                      const float* __restrict__ Wk,
                      const float* __restrict__ Wv,
                      float*       __restrict__ out)
{
    __shared__ float red[256];
    __shared__ float vec[64];          // qbar -> qw -> kbar (reused across barriers)
    __shared__ float qks[64];
    __shared__ float scr[64 * 65];     // token-partial kacc transpose (pad 65: <=2-way)
    __shared__ float sS[4];

    const int tid  = threadIdx.x;
    const int b    = blockIdx.x;
    const int lane = tid & 63;
    const int wave = tid >> 6;
    const int tok  = tid >> 2;         // 0..63: token slot
    const int dq   = (tid & 3) << 4;   // 16-float slice of D

    const float* kb = k + (size_t)b * (MAXLEN * 64);
    const float* qb = q + (size_t)b * (64 * 64);   // F == D == 64

    // ---- prefetch k chunk 0 (t = tok, always < 200) into registers
    float4 cur[4], nxt[4];
    {
        const float4* kr = (const float4*)(kb + tok * 64 + dq);
        cur[0] = kr[0]; cur[1] = kr[1]; cur[2] = kr[2]; cur[3] = kr[3];
    }
    const int len = kes_length[b];

    // ---- qbar[d] = sum_f fs[f] * q[b,f,d]
    float acc = 0.f;
    #pragma unroll
    for (int i = 0; i < 16; ++i) {
        const int f = wave * 16 + i;
        acc += fs[f] * qb[f * 64 + lane];
    }
    red[tid] = acc;
    __syncthreads();
    if (tid < 64) vec[tid] = red[tid] + red[tid + 64] + red[tid + 128] + red[tid + 192];
    __syncthreads();

    // ---- qw[e] = sum_d qbar[d] * Wq[d,e]
    acc = 0.f;
    #pragma unroll
    for (int i = 0; i < 16; ++i) {
        const int dd = wave * 16 + i;
        acc += vec[dd] * Wq[dd * 64 + lane];
    }
    red[tid] = acc;
    __syncthreads();
    if (tid < 64) vec[tid] = red[tid] + red[tid + 64] + red[tid + 128] + red[tid + 192];
    __syncthreads();

    // ---- qk[d] = sum_e Wk[d,e] * qw[e]   (Wk 16 KB, L1/L2-hot across blocks)
    acc = 0.f;
    #pragma unroll
    for (int i = 0; i < 16; ++i) {
        const int e = wave * 16 + i;
        acc += Wk[lane * 64 + e] * vec[e];
    }
    red[tid] = acc;
    __syncthreads();
    if (tid < 64) qks[tid] = red[tid] + red[tid + 64] + red[tid + 128] + red[tid + 192];
    __syncthreads();

    // each thread's 16-float slice of qk -> registers (broadcast reads, free)
    float qkreg[16];
    {
        const float4* qp = (const float4*)(qks + dq);
        #pragma unroll
        for (int j = 0; j < 4; ++j) {
            const float4 t4 = qp[j];
            qkreg[j*4+0] = t4.x; qkreg[j*4+1] = t4.y;
            qkreg[j*4+2] = t4.z; qkreg[j*4+3] = t4.w;
        }
    }

    const float bscale = bias[0] * 64.0f;

    // ---- main loop: 4 chunks of 64 tokens, k in registers, no barriers
    float kacc[16];
    #pragma unroll
    for (int i = 0; i < 16; ++i) kacc[i] = 0.f;
    float Sr = 0.f;

    #pragma unroll
    for (int c = 0; c < 4; ++c) {
        if (c < 3) {                       // prefetch next chunk
            const int tn = (c + 1) * 64 + tok;
            if (tn < MAXLEN) {
                const float4* kr = (const float4*)(kb + tn * 64 + dq);
                nxt[0] = kr[0]; nxt[1] = kr[1]; nxt[2] = kr[2]; nxt[3] = kr[3];
            }
        }
        const int t = c * 64 + tok;
        const float* cf = (const float*)cur;
        float s = 0.f;
        #pragma unroll
        for (int i = 0; i < 16; ++i) s += cf[i] * qkreg[i];
        s += __shfl_xor(s, 1);             // combine the 4 slice-lanes
        s += __shfl_xor(s, 2);
        s += bscale;
        float w = 0.f;
        if (t < MAXLEN) {
            if (len == 0)      w = 1.0f;                           // uniform softmax
            else if (t < len) { const float sig = 1.0f / (1.0f + __expf(-s));
                                w = __expf(sig * 0.125f); }        // no max-shift
            // else masked: w stays 0 (exact)
        }
        #pragma unroll
        for (int i = 0; i < 16; ++i) kacc[i] += w * cf[i];
        Sr += w;                           // slice-redundant; reduced over toks only
        if (c < 3) {
            cur[0] = nxt[0]; cur[1] = nxt[1]; cur[2] = nxt[2]; cur[3] = nxt[3];
        }
    }

    // ---- S = sum_t w  (reduce across the 16 tokens of each wave, then 4 waves)
    float Sw = Sr;
    Sw += __shfl_xor(Sw, 4);
    Sw += __shfl_xor(Sw, 8);
    Sw += __shfl_xor(Sw, 16);
    Sw += __shfl_xor(Sw, 32);
    if (lane == 0) sS[wave] = Sw;

    // ---- reduce kacc across the 64 token slots via LDS transpose
    #pragma unroll
    for (int i = 0; i < 16; ++i) scr[tok * 65 + dq + i] = kacc[i];
    __syncthreads();
    const float S = sS[0] + sS[1] + sS[2] + sS[3];     // >= 1 always
    acc = 0.f;
    #pragma unroll
    for (int i = 0; i < 16; ++i) {
        const int row = wave * 16 + i;
        acc += scr[row * 65 + lane];       // banks (row+lane)%32 -> 2-way, free
    }
    red[tid] = acc;
    __syncthreads();
    if (tid < 64)
        vec[tid] = (red[tid] + red[tid + 64] + red[tid + 128] + red[tid + 192]) / S;
    __syncthreads();

    // ---- out[b] = kbar @ Wv
    acc = 0.f;
    #pragma unroll
    for (int i = 0; i < 16; ++i) {
        const int dd = wave * 16 + i;
        acc += vec[dd] * Wv[dd * 64 + lane];
    }
    red[tid] = acc;
    __syncthreads();
    if (tid < 64)
        out[(size_t)b * 64 + tid] = red[tid] + red[tid + 64] + red[tid + 128] + red[tid + 192];
}
} // namespace

extern "C" void kernel_launch(void* const* d_in, const int* in_sizes, int n_in,
                              void* d_out, int out_size, void* d_ws, size_t ws_size,
                              hipStream_t stream) {
    const float* q    = (const float*)d_in[0];
    const float* k    = (const float*)d_in[1];
    // d_in[2] = v : unused by the reference (vp is computed from k)
    const int*   kes  = (const int*)  d_in[3];
    const float* fs   = (const float*)d_in[4];
    const float* bias = (const float*)d_in[5];
    const float* Wq   = (const float*)d_in[6];
    const float* Wk   = (const float*)d_in[7];
    const float* Wv   = (const float*)d_in[8];
    float* out = (float*)d_out;

    auto_attn_kernel<<<dim3(1024), dim3(256), 0, stream>>>(q, k, kes, fs, bias, Wq, Wk, Wv, out);
}

// Round 4
// 138.475 us; speedup vs baseline: 1.0286x; 1.0130x over previous
//
#include <hip/hip_runtime.h>
#include <math.h>

// AutoAttention_Layer: B=1024, MAXLEN=200, F=64, D=64, fp32.
// Algebra: v unused; the three DxD projections collapse to per-batch 64-GEMVs
// (qbar = sum_f fs[f] q[b,f,:]; qw = qbar@Wq; qk = Wk@qw; out = kbar@Wv);
// single-pass softmax: unmasked logits = sigmoid(.)/8 in (0,0.125) -> exp needs
// no max-shift; masked exp underflows to exactly 0; len==0 -> uniform weights.
// Structure: k never touches LDS. 4 threads per token hold 16-float k slices in
// registers; score completed via 2x shfl_xor; weighted k accumulated in 16
// VGPRs; one small LDS transpose at the end.
// NEW: len-aware chunk skipping — tokens >= len have weight exactly 0, so
// chunks with c*64 >= len are neither loaded nor processed (len==0 excepted:
// uniform softmax needs all 200 tokens). Cuts avg k traffic ~2x.

namespace {
constexpr int MAXLEN = 200;

__global__ __launch_bounds__(256, 4)   // 4 waves/EU -> 4 blocks/CU; VGPR cap 128
void auto_attn_kernel(const float* __restrict__ q,
                      const float* __restrict__ k,
                      const int*   __restrict__ kes_length,
                      const float* __restrict__ fs,
                      const float* __restrict__ bias,
                      const float* __restrict__ Wq,
                      const float* __restrict__ Wk,
                      const float* __restrict__ Wv,
                      float*       __restrict__ out)
{
    __shared__ float red[256];
    __shared__ float vec[64];          // qbar -> qw -> kbar (reused across barriers)
    __shared__ float qks[64];
    __shared__ float scr[64 * 65];     // token-partial kacc transpose (pad 65: <=2-way)
    __shared__ float sS[4];

    const int tid  = threadIdx.x;
    const int b    = blockIdx.x;
    const int lane = tid & 63;
    const int wave = tid >> 6;
    const int tok  = tid >> 2;         // 0..63: token slot
    const int dq   = (tid & 3) << 4;   // 16-float slice of D

    const float* kb = k + (size_t)b * (MAXLEN * 64);
    const float* qb = q + (size_t)b * (64 * 64);   // F == D == 64

    const int len = kes_length[b];
    // chunks actually contributing: len==0 -> all 4 (uniform softmax);
    // else ceil(len/64) (tokens >= len have weight exactly 0)
    const int nc = (len == 0) ? 4 : min(4, (len + 63) >> 6);

    // ---- prefetch k chunk 0 (t = tok, always < 200) into registers
    float4 cur[4], nxt[4];
    {
        const float4* kr = (const float4*)(kb + tok * 64 + dq);
        cur[0] = kr[0]; cur[1] = kr[1]; cur[2] = kr[2]; cur[3] = kr[3];
    }

    // ---- qbar[d] = sum_f fs[f] * q[b,f,d]
    float acc = 0.f;
    #pragma unroll
    for (int i = 0; i < 16; ++i) {
        const int f = wave * 16 + i;
        acc += fs[f] * qb[f * 64 + lane];
    }
    red[tid] = acc;
    __syncthreads();
    if (tid < 64) vec[tid] = red[tid] + red[tid + 64] + red[tid + 128] + red[tid + 192];
    __syncthreads();

    // ---- qw[e] = sum_d qbar[d] * Wq[d,e]
    acc = 0.f;
    #pragma unroll
    for (int i = 0; i < 16; ++i) {
        const int dd = wave * 16 + i;
        acc += vec[dd] * Wq[dd * 64 + lane];
    }
    red[tid] = acc;
    __syncthreads();
    if (tid < 64) vec[tid] = red[tid] + red[tid + 64] + red[tid + 128] + red[tid + 192];
    __syncthreads();

    // ---- qk[d] = sum_e Wk[d,e] * qw[e]   (Wk 16 KB, L1/L2-hot across blocks)
    acc = 0.f;
    #pragma unroll
    for (int i = 0; i < 16; ++i) {
        const int e = wave * 16 + i;
        acc += Wk[lane * 64 + e] * vec[e];
    }
    red[tid] = acc;
    __syncthreads();
    if (tid < 64) qks[tid] = red[tid] + red[tid + 64] + red[tid + 128] + red[tid + 192];
    __syncthreads();

    // each thread's 16-float slice of qk -> registers (broadcast reads, free)
    float qkreg[16];
    {
        const float4* qp = (const float4*)(qks + dq);
        #pragma unroll
        for (int j = 0; j < 4; ++j) {
            const float4 t4 = qp[j];
            qkreg[j*4+0] = t4.x; qkreg[j*4+1] = t4.y;
            qkreg[j*4+2] = t4.z; qkreg[j*4+3] = t4.w;
        }
    }

    const float bscale = bias[0] * 64.0f;

    // ---- main loop over needed chunks only; k in registers, no barriers
    float kacc[16];
    #pragma unroll
    for (int i = 0; i < 16; ++i) kacc[i] = 0.f;
    float Sr = 0.f;

    for (int c = 0; c < nc; ++c) {
        if (c + 1 < nc) {                  // prefetch next needed chunk
            const int tn = (c + 1) * 64 + tok;
            if (tn < MAXLEN) {
                const float4* kr = (const float4*)(kb + tn * 64 + dq);
                nxt[0] = kr[0]; nxt[1] = kr[1]; nxt[2] = kr[2]; nxt[3] = kr[3];
            }
        }
        const int t = c * 64 + tok;
        const float* cf = (const float*)cur;
        float s = 0.f;
        #pragma unroll
        for (int i = 0; i < 16; ++i) s += cf[i] * qkreg[i];
        s += __shfl_xor(s, 1);             // combine the 4 slice-lanes
        s += __shfl_xor(s, 2);
        s += bscale;
        float w = 0.f;
        if (t < MAXLEN) {
            if (len == 0)      w = 1.0f;                           // uniform softmax
            else if (t < len) { const float sig = 1.0f / (1.0f + __expf(-s));
                                w = __expf(sig * 0.125f); }        // no max-shift
            // else masked: w stays 0 (exact)
        }
        #pragma unroll
        for (int i = 0; i < 16; ++i) kacc[i] += w * cf[i];
        Sr += w;                           // slice-redundant; reduced over toks only
        if (c + 1 < nc) {
            cur[0] = nxt[0]; cur[1] = nxt[1]; cur[2] = nxt[2]; cur[3] = nxt[3];
        }
    }

    // ---- S = sum_t w  (reduce across the 16 tokens of each wave, then 4 waves)
    float Sw = Sr;
    Sw += __shfl_xor(Sw, 4);
    Sw += __shfl_xor(Sw, 8);
    Sw += __shfl_xor(Sw, 16);
    Sw += __shfl_xor(Sw, 32);
    if (lane == 0) sS[wave] = Sw;

    // ---- reduce kacc across the 64 token slots via LDS transpose
    #pragma unroll
    for (int i = 0; i < 16; ++i) scr[tok * 65 + dq + i] = kacc[i];
    __syncthreads();
    const float S = sS[0] + sS[1] + sS[2] + sS[3];     // >= 1 always
    acc = 0.f;
    #pragma unroll
    for (int i = 0; i < 16; ++i) {
        const int row = wave * 16 + i;
        acc += scr[row * 65 + lane];       // banks (row+lane)%32 -> 2-way, free
    }
    red[tid] = acc;
    __syncthreads();
    if (tid < 64)
        vec[tid] = (red[tid] + red[tid + 64] + red[tid + 128] + red[tid + 192]) / S;
    __syncthreads();

    // ---- out[b] = kbar @ Wv
    acc = 0.f;
    #pragma unroll
    for (int i = 0; i < 16; ++i) {
        const int dd = wave * 16 + i;
        acc += vec[dd] * Wv[dd * 64 + lane];
    }
    red[tid] = acc;
    __syncthreads();
    if (tid < 64)
        out[(size_t)b * 64 + tid] = red[tid] + red[tid + 64] + red[tid + 128] + red[tid + 192];
}
} // namespace

extern "C" void kernel_launch(void* const* d_in, const int* in_sizes, int n_in,
                              void* d_out, int out_size, void* d_ws, size_t ws_size,
                              hipStream_t stream) {
    const float* q    = (const float*)d_in[0];
    const float* k    = (const float*)d_in[1];
    // d_in[2] = v : unused by the reference (vp is computed from k)
    const int*   kes  = (const int*)  d_in[3];
    const float* fs   = (const float*)d_in[4];
    const float* bias = (const float*)d_in[5];
    const float* Wq   = (const float*)d_in[6];
    const float* Wk   = (const float*)d_in[7];
    const float* Wv   = (const float*)d_in[8];
    float* out = (float*)d_out;

    auto_attn_kernel<<<dim3(1024), dim3(256), 0, stream>>>(q, k, kes, fs, bias, Wq, Wk, Wv, out);
}